// Round 1
// baseline (555.179 us; speedup 1.0000x reference)
//
#include <hip/hip_runtime.h>
#include <hip/hip_bf16.h>
#include <cstdint>
#include <cstddef>

// TransformerEncoderLayer: B=2 S=2048 D=1024 H=16 DH=64 DFF=4096, fp32 in/out.
// Round 0: correctness-first full pipeline, bf16 MFMA GEMMs (m97-style 128x128,
// BK=64, global_load_lds w16, XOR-swizzled LDS), flash attention, fused epilogues.

#define SB 2048
#define DD 1024
#define NB 2
#define NH 16
#define DFF_ 4096
#define NTOK (NB*SB)   // 4096
#define SP (SB+2)      // 2050 (padded rows for conv halo)

typedef unsigned short u16;
typedef float f32x4 __attribute__((ext_vector_type(4)));
typedef short s16x8 __attribute__((ext_vector_type(8)));

__device__ __forceinline__ u16 f2b(float f){
  uint32_t u = __builtin_bit_cast(uint32_t, f);
  return (u16)((u + 0x7fffu + ((u >> 16) & 1u)) >> 16);  // RNE
}

// ---------------- workspace layout (bytes) ----------------
constexpr size_t OFF_CW1   = 0;                                     // 3x1024x1024 bf16
constexpr size_t OFF_CW2   = OFF_CW1 + 3ull*1024*1024*2;
constexpr size_t OFF_WQKV  = OFF_CW2 + 3ull*1024*1024*2;            // 3072x1024 bf16 (q scaled 1/8)
constexpr size_t OFF_WO    = OFF_WQKV + 3072ull*1024*2;
constexpr size_t OFF_W1    = OFF_WO + 1024ull*1024*2;
constexpr size_t OFF_W2    = OFF_W1 + 4096ull*1024*2;
constexpr size_t OFF_PRE   = OFF_W2 + 4096ull*1024*2;               // f32 4096x1024
constexpr size_t OFF_QKVB  = OFF_PRE + (size_t)NTOK*1024*4;         // bf16 4096x3072
constexpr size_t OFF_INTER = OFF_PRE;                               // alias: bf16 4096x4096 (pre+qkvb dead)
constexpr size_t OFF_XPAD  = OFF_QKVB + (size_t)NTOK*3072*2;        // bf16 2x2050x1024
constexpr size_t OFF_LNF   = OFF_XPAD;                              // alias (xpad dead after conv1)
constexpr size_t OFF_HPAD  = OFF_XPAD + (size_t)NB*SP*1024*2;       // bf16 2x2050x1024
constexpr size_t OFF_CTX   = OFF_HPAD;                              // alias (hpad dead after conv2)
constexpr size_t OFF_INPUTS= OFF_HPAD + (size_t)NB*SP*1024*2;       // f32 4096x1024
constexpr size_t OFF_XN    = OFF_INPUTS + (size_t)NTOK*1024*4;      // bf16 4096x1024

// ---------------- pack kernels ----------------
__global__ void pack_scale_k(const float* __restrict__ in, u16* __restrict__ out, int n, float scale){
  int i = blockIdx.x*256 + threadIdx.x;
  if (i < n) out[i] = f2b(in[i]*scale);
}

// w[o][i][t] (D,D,3) -> out[t][o][i] bf16
__global__ void pack_convw_k(const float* __restrict__ w, u16* __restrict__ out){
  int i = blockIdx.x*256 + threadIdx.x;   // over 3*1024*1024
  int t = i >> 20;
  int rem = i & 1048575;
  int o = rem >> 10;
  int c = rem & 1023;
  out[i] = f2b(w[o*3072 + c*3 + t]);
}

// x f32 (B,S,D) -> xpad bf16 (B,S+2,D), zero halo rows
__global__ void pad_x_k(const float* __restrict__ x, u16* __restrict__ xp){
  int row = blockIdx.x;  // 0..NB*SP-1
  int tid = threadIdx.x;
  int b = row / SP, s = row - b*SP;
  ushort4 st;
  if (s == 0 || s == SP-1){ st.x=0; st.y=0; st.z=0; st.w=0; }
  else {
    float4 v = ((const float4*)(x + ((size_t)b*SB + s-1)*DD))[tid];
    st.x=f2b(v.x); st.y=f2b(v.y); st.z=f2b(v.z); st.w=f2b(v.w);
  }
  ((ushort4*)(xp + (size_t)row*DD))[tid] = st;
}

// ---------------- LayerNorm ----------------
// MODE 0: relu(in+cb) -> LN -> bf16 PADDED out (grid NB*SP, halo rows zeroed)
// MODE 1: relu(in+cb) -> LN -> + resid -> f32 out (grid NTOK)
// MODE 2: LN(in) -> bf16 out (grid NTOK)
template<int MODE>
__global__ __launch_bounds__(256) void ln_k(const float* __restrict__ in, const float* __restrict__ cb,
    const float* __restrict__ g, const float* __restrict__ be, const float* __restrict__ resid,
    float* __restrict__ outf, u16* __restrict__ outb)
{
  int row = blockIdx.x, tid = threadIdx.x;
  int inrow = row;
  if (MODE == 0){
    int b = row / SP, s = row - b*SP;
    if (s == 0 || s == SP-1){
      ushort4 z; z.x=0; z.y=0; z.z=0; z.w=0;
      ((ushort4*)(outb + (size_t)row*DD))[tid] = z;
      return;
    }
    inrow = b*SB + s - 1;
  }
  float4 v = ((const float4*)(in + (size_t)inrow*DD))[tid];
  if (MODE <= 1){
    float4 c = ((const float4*)cb)[tid];
    v.x = fmaxf(v.x + c.x, 0.f);
    v.y = fmaxf(v.y + c.y, 0.f);
    v.z = fmaxf(v.z + c.z, 0.f);
    v.w = fmaxf(v.w + c.w, 0.f);
  }
  float s1 = v.x+v.y+v.z+v.w;
  float s2 = v.x*v.x + v.y*v.y + v.z*v.z + v.w*v.w;
  #pragma unroll
  for (int d=32; d>=1; d>>=1){ s1 += __shfl_down(s1, d); s2 += __shfl_down(s2, d); }
  __shared__ float red[8];
  int wid = tid >> 6, lane = tid & 63;
  if (lane==0){ red[wid] = s1; red[4+wid] = s2; }
  __syncthreads();
  s1 = red[0]+red[1]+red[2]+red[3];
  s2 = red[4]+red[5]+red[6]+red[7];
  float mu = s1 * (1.f/DD);
  float var = s2 * (1.f/DD) - mu*mu;
  float rs = rsqrtf(var + 1e-6f);
  float4 gg = ((const float4*)g)[tid];
  float4 bb = ((const float4*)be)[tid];
  float o0 = (v.x-mu)*rs*gg.x + bb.x;
  float o1 = (v.y-mu)*rs*gg.y + bb.y;
  float o2 = (v.z-mu)*rs*gg.z + bb.z;
  float o3 = (v.w-mu)*rs*gg.w + bb.w;
  if (MODE == 1){
    float4 rr = ((const float4*)(resid + (size_t)inrow*DD))[tid];
    float4 o; o.x=o0+rr.x; o.y=o1+rr.y; o.z=o2+rr.z; o.w=o3+rr.w;
    ((float4*)(outf + (size_t)inrow*DD))[tid] = o;
  } else {
    ushort4 st; st.x=f2b(o0); st.y=f2b(o1); st.z=f2b(o2); st.w=f2b(o3);
    ((ushort4*)(outb + (size_t)row*DD))[tid] = st;
  }
}

// ---------------- GEMM core (C = A @ B^T), bf16 in, fp32 accum ----------------
// BM=BN=128, BK=64, 256 threads (4 waves, 2x2), mfma 16x16x32 bf16.
// LDS layout: [128 rows][64 cols] bf16 (128B rows), XOR-swizzle byte^=((row&7)<<4)
// applied by pre-swizzling the GLOBAL source address (global_load_lds writes linearly).

__device__ __forceinline__ void glds16(const u16* g, u16* l){
  __builtin_amdgcn_global_load_lds((const __attribute__((address_space(1))) void*)g,
                                   (__attribute__((address_space(3))) void*)l, 16, 0, 0);
}

__device__ __forceinline__ void stage_tile(const u16* __restrict__ src, int strideK, u16* lds, int wid, int lane){
  #pragma unroll
  for (int i=0;i<4;i++){
    int chunk = (wid<<2) + i;            // 16 chunks x 1KB cover 128x64 bf16
    int p = (chunk<<10) + (lane<<4);     // linear LDS byte this lane fills
    int row = p >> 7;
    int clg = (p & 127) ^ ((row & 7) << 4);   // logical col byte stored here
    glds16(src + (size_t)row*strideK + (clg>>1), lds + (chunk<<9));
  }
}

__device__ __forceinline__ void kstep_mfma(const u16* As, const u16* Bs, int wr, int wc, int lr, int hi, f32x4 acc[4][4]){
  s16x8 af[2][4], bf[2][4];
  #pragma unroll
  for (int ks=0; ks<2; ++ks){
    #pragma unroll
    for (int m=0;m<4;m++){
      int r = (wr<<6)+(m<<4)+lr;
      int off = (r<<7) + ((((ks<<6)+(hi<<4))) ^ ((r&7)<<4));
      af[ks][m] = *(const s16x8*)((const char*)As + off);
    }
    #pragma unroll
    for (int n=0;n<4;n++){
      int r = (wc<<6)+(n<<4)+lr;
      int off = (r<<7) + ((((ks<<6)+(hi<<4))) ^ ((r&7)<<4));
      bf[ks][n] = *(const s16x8*)((const char*)Bs + off);
    }
  }
  #pragma unroll
  for (int ks=0;ks<2;++ks)
    #pragma unroll
    for (int m=0;m<4;m++)
      #pragma unroll
      for (int n=0;n<4;n++)
        acc[m][n] = __builtin_amdgcn_mfma_f32_16x16x32_bf16(af[ks][m], bf[ks][n], acc[m][n], 0,0,0);
}

// EPI flags: 1=bias[col], 2=relu, 4=+resid f32[row*N+col], 8=*rowmask[row], 16=bf16 out (else f32)
template<int EPI>
__device__ __forceinline__ void epilogue(f32x4 acc[4][4], int m0,int n0,int N,int wr,int wc,int lr,int hi,
    const float* __restrict__ bias, const float* __restrict__ resid, const float* __restrict__ rowmask,
    float* __restrict__ Cf, u16* __restrict__ Cb)
{
  #pragma unroll
  for (int m=0;m<4;m++){
    #pragma unroll
    for (int r=0;r<4;r++){
      int row = m0 + (wr<<6) + (m<<4) + (hi<<2) + r;
      float rm = (EPI&8) ? rowmask[row] : 1.f;
      #pragma unroll
      for (int n=0;n<4;n++){
        int col = n0 + (wc<<6) + (n<<4) + lr;
        float v = acc[m][n][r];
        if (EPI&1) v += bias[col];
        if (EPI&2) v = fmaxf(v, 0.f);
        if (EPI&8) v *= rm;
        if (EPI&4) v += resid[(size_t)row*N + col];
        if (EPI&16) Cb[(size_t)row*N + col] = f2b(v);
        else        Cf[(size_t)row*N + col] = v;
      }
    }
  }
}

template<int EPI>
__global__ __launch_bounds__(256) void gemm_bt(const u16* __restrict__ A, const u16* __restrict__ Bm,
    int N, int K, const float* __restrict__ bias, const float* __restrict__ resid,
    const float* __restrict__ rowmask, float* __restrict__ Cf, u16* __restrict__ Cb)
{
  __shared__ __attribute__((aligned(16))) u16 As[128*64];
  __shared__ __attribute__((aligned(16))) u16 Bs[128*64];
  int tid=threadIdx.x, wid=tid>>6, lane=tid&63, lr=lane&15, hi=lane>>4;
  int wr=wid>>1, wc=wid&1;
  int m0=blockIdx.x<<7, n0=blockIdx.y<<7;
  f32x4 acc[4][4] = {};
  const u16* Ab = A + (size_t)m0*K;
  const u16* Bb = Bm + (size_t)n0*K;
  int nk = K >> 6;
  for (int kt=0; kt<nk; ++kt){
    stage_tile(Ab + (kt<<6), K, As, wid, lane);
    stage_tile(Bb + (kt<<6), K, Bs, wid, lane);
    __syncthreads();
    kstep_mfma(As, Bs, wr, wc, lr, hi, acc);
    __syncthreads();
  }
  epilogue<EPI>(acc, m0, n0, N, wr, wc, lr, hi, bias, resid, rowmask, Cf, Cb);
}

// conv as GEMM over padded activations: out[s][o] = sum_t sum_i xp[b][s+t][i]*W3[t][o][i]
__global__ __launch_bounds__(256) void conv_gemm(const u16* __restrict__ xp, const u16* __restrict__ W3,
    float* __restrict__ Cf)
{
  __shared__ __attribute__((aligned(16))) u16 As[128*64];
  __shared__ __attribute__((aligned(16))) u16 Bs[128*64];
  int tid=threadIdx.x, wid=tid>>6, lane=tid&63, lr=lane&15, hi=lane>>4;
  int wr=wid>>1, wc=wid&1;
  int m0=blockIdx.x<<7, n0=blockIdx.y<<7;
  int bb = m0 >> 11, ss = m0 & 2047;   // 2048 rows per batch; tiles never cross batches
  f32x4 acc[4][4] = {};
  for (int tap=0; tap<3; ++tap){
    const u16* Ab = xp + ((size_t)bb*SP + ss + tap)*DD;
    const u16* Bb = W3 + ((size_t)tap<<20) + ((size_t)n0<<10);
    for (int kt=0; kt<16; ++kt){
      stage_tile(Ab + (kt<<6), DD, As, wid, lane);
      stage_tile(Bb + (kt<<6), DD, Bs, wid, lane);
      __syncthreads();
      kstep_mfma(As, Bs, wr, wc, lr, hi, acc);
      __syncthreads();
    }
  }
  epilogue<0>(acc, m0, n0, DD, wr, wc, lr, hi, nullptr, nullptr, nullptr, Cf, nullptr);
}

// ---------------- flash attention ----------------
// qkv: [NTOK][3072] bf16 rows = [q(1024) k(1024) v(1024)], q pre-scaled 1/8.
// grid (S/64, H, B), 256 threads; wave w owns 16 q-rows. kv-tile = 32 keys.
__global__ __launch_bounds__(256) void attn_k(const u16* __restrict__ qkv, u16* __restrict__ ctx)
{
  __shared__ __attribute__((aligned(16))) u16 Ks[32][72];   // [key][d], pad->2-way reads
  __shared__ __attribute__((aligned(16))) u16 Vt[64][40];   // [d][key] (transposed)
  __shared__ __attribute__((aligned(16))) u16 Ps[4][16][40];// per-wave P tile [qrow][key]
  int tid=threadIdx.x, wid=tid>>6, lane=tid&63, lr=lane&15, hi=lane>>4;
  int qt=blockIdx.x, h=blockIdx.y, b=blockIdx.z;
  int q0 = (qt<<6) + (wid<<4);
  size_t qrow = ((size_t)b*SB + q0 + lr)*3072 + (h<<6);
  s16x8 aq0 = *(const s16x8*)(qkv + qrow + (hi<<3));        // d 0..31
  s16x8 aq1 = *(const s16x8*)(qkv + qrow + 32 + (hi<<3));   // d 32..63
  float m_r[4] = {-1e30f,-1e30f,-1e30f,-1e30f};
  float l_r[4] = {0.f,0.f,0.f,0.f};
  f32x4 zero4 = {0.f,0.f,0.f,0.f};
  f32x4 acc[4]; acc[0]=zero4; acc[1]=zero4; acc[2]=zero4; acc[3]=zero4;
  int srow = tid>>3, sdc = (tid&7)<<3;
  size_t kbase = ((size_t)b*SB)*3072 + 1024 + (h<<6);
  size_t vbase = ((size_t)b*SB)*3072 + 2048 + (h<<6);
  for (int kt=0; kt<64; ++kt){
    int k0 = kt<<5;
    __syncthreads();                       // prev-iter reads done before restage
    *(s16x8*)&Ks[srow][sdc] = *(const s16x8*)(qkv + kbase + (size_t)(k0+srow)*3072 + sdc);
    {
      s16x8 vv = *(const s16x8*)(qkv + vbase + (size_t)(k0+srow)*3072 + sdc);
      #pragma unroll
      for (int j=0;j<8;j++) Vt[sdc+j][srow] = (u16)vv[j];
    }
    __syncthreads();
    f32x4 s0 = zero4, s1 = zero4;
    s16x8 kb;
    kb = *(const s16x8*)&Ks[lr][hi<<3];          s0 = __builtin_amdgcn_mfma_f32_16x16x32_bf16(aq0, kb, s0,0,0,0);
    kb = *(const s16x8*)&Ks[lr][32+(hi<<3)];     s0 = __builtin_amdgcn_mfma_f32_16x16x32_bf16(aq1, kb, s0,0,0,0);
    kb = *(const s16x8*)&Ks[16+lr][hi<<3];       s1 = __builtin_amdgcn_mfma_f32_16x16x32_bf16(aq0, kb, s1,0,0,0);
    kb = *(const s16x8*)&Ks[16+lr][32+(hi<<3)];  s1 = __builtin_amdgcn_mfma_f32_16x16x32_bf16(aq1, kb, s1,0,0,0);
    // online softmax; D-frag: col(key)=lr, row(q)=hi*4+r; rows live in 16-lane groups
    #pragma unroll
    for (int r=0;r<4;r++){
      float mt = fmaxf(s0[r], s1[r]);
      #pragma unroll
      for (int d=1; d<16; d<<=1) mt = fmaxf(mt, __shfl_xor(mt, d));
      float mn = fmaxf(m_r[r], mt);
      float al = __expf(m_r[r] - mn);
      float p0 = __expf(s0[r] - mn);
      float p1 = __expf(s1[r] - mn);
      float sm = p0 + p1;
      #pragma unroll
      for (int d=1; d<16; d<<=1) sm += __shfl_xor(sm, d);
      l_r[r] = l_r[r]*al + sm;
      m_r[r] = mn;
      acc[0][r]*=al; acc[1][r]*=al; acc[2][r]*=al; acc[3][r]*=al;
      Ps[wid][(hi<<2)+r][lr]    = f2b(p0);
      Ps[wid][(hi<<2)+r][16+lr] = f2b(p1);
    }
    // PV: A=P (row=q=lr, k=key=hi*8+j), B=V (k=key, col=d=lr per 16-col group)
    s16x8 pa = *(const s16x8*)&Ps[wid][lr][hi<<3];
    #pragma unroll
    for (int cg=0; cg<4; cg++){
      s16x8 vb = *(const s16x8*)&Vt[(cg<<4)+lr][hi<<3];
      acc[cg] = __builtin_amdgcn_mfma_f32_16x16x32_bf16(pa, vb, acc[cg],0,0,0);
    }
  }
  size_t obase = ((size_t)b*SB + q0)*DD + (h<<6);
  #pragma unroll
  for (int r=0;r<4;r++){
    float inv = 1.f / l_r[r];
    #pragma unroll
    for (int cg=0; cg<4; cg++)
      ctx[obase + (size_t)((hi<<2)+r)*DD + (cg<<4) + lr] = f2b(acc[cg][r]*inv);
  }
}

// ---------------- launch ----------------
extern "C" void kernel_launch(void* const* d_in, const int* in_sizes, int n_in,
                              void* d_out, int out_size, void* d_ws, size_t ws_size,
                              hipStream_t stream)
{
  (void)in_sizes; (void)n_in; (void)out_size; (void)ws_size;
  const float* x       = (const float*)d_in[0];
  const float* ffnmask = (const float*)d_in[2];
  const float* conv1_w = (const float*)d_in[3];
  const float* conv1_b = (const float*)d_in[4];
  const float* ln1_g   = (const float*)d_in[5];
  const float* ln1_b   = (const float*)d_in[6];
  const float* conv2_w = (const float*)d_in[7];
  const float* conv2_b = (const float*)d_in[8];
  const float* ln2_g   = (const float*)d_in[9];
  const float* ln2_b   = (const float*)d_in[10];
  const float* lnA_g   = (const float*)d_in[11];
  const float* lnA_b   = (const float*)d_in[12];
  const float* Wq      = (const float*)d_in[13];
  const float* Wk      = (const float*)d_in[14];
  const float* Wv      = (const float*)d_in[15];
  const float* Wo      = (const float*)d_in[16];
  const float* lnF_g   = (const float*)d_in[17];
  const float* lnF_b   = (const float*)d_in[18];
  const float* W1      = (const float*)d_in[19];
  const float* b1      = (const float*)d_in[20];
  const float* W2      = (const float*)d_in[21];
  const float* b2      = (const float*)d_in[22];
  float* out = (float*)d_out;
  char* ws = (char*)d_ws;
  u16*  cw1    = (u16*)(ws + OFF_CW1);
  u16*  cw2    = (u16*)(ws + OFF_CW2);
  u16*  wqkv   = (u16*)(ws + OFF_WQKV);
  u16*  wo     = (u16*)(ws + OFF_WO);
  u16*  w1p    = (u16*)(ws + OFF_W1);
  u16*  w2p    = (u16*)(ws + OFF_W2);
  float* pre   = (float*)(ws + OFF_PRE);
  u16*  qkvb   = (u16*)(ws + OFF_QKVB);
  u16*  interb = (u16*)(ws + OFF_INTER);
  u16*  xpad   = (u16*)(ws + OFF_XPAD);
  u16*  lnfb   = (u16*)(ws + OFF_LNF);
  u16*  hpad   = (u16*)(ws + OFF_HPAD);
  u16*  ctxb   = (u16*)(ws + OFF_CTX);
  float* inputs= (float*)(ws + OFF_INPUTS);
  u16*  xnb    = (u16*)(ws + OFF_XN);

  // weight packs (bf16); q-scale 1/sqrt(64) folded into Wq
  pack_convw_k<<<12288, 256, 0, stream>>>(conv1_w, cw1);
  pack_convw_k<<<12288, 256, 0, stream>>>(conv2_w, cw2);
  pack_scale_k<<<4096, 256, 0, stream>>>(Wq, wqkv,             1024*1024, 0.125f);
  pack_scale_k<<<4096, 256, 0, stream>>>(Wk, wqkv + (1u<<20),  1024*1024, 1.f);
  pack_scale_k<<<4096, 256, 0, stream>>>(Wv, wqkv + (2u<<20),  1024*1024, 1.f);
  pack_scale_k<<<4096, 256, 0, stream>>>(Wo, wo,               1024*1024, 1.f);
  pack_scale_k<<<16384, 256, 0, stream>>>(W1, w1p, 4096*1024, 1.f);
  pack_scale_k<<<16384, 256, 0, stream>>>(W2, w2p, 4096*1024, 1.f);
  pad_x_k<<<NB*SP, 256, 0, stream>>>(x, xpad);

  // conv1 -> relu -> LN1 (padded bf16 for conv2)
  conv_gemm<<<dim3(32,8), 256, 0, stream>>>(xpad, cw1, pre);
  ln_k<0><<<NB*SP, 256, 0, stream>>>(pre, conv1_b, ln1_g, ln1_b, nullptr, nullptr, hpad);
  // conv2 -> relu -> LN2 -> +x  => inputs (f32)
  conv_gemm<<<dim3(32,8), 256, 0, stream>>>(hpad, cw2, pre);
  ln_k<1><<<NTOK, 256, 0, stream>>>(pre, conv2_b, ln2_g, ln2_b, x, inputs, nullptr);
  // lnA -> xn (bf16)
  ln_k<2><<<NTOK, 256, 0, stream>>>(inputs, nullptr, lnA_g, lnA_b, nullptr, nullptr, xnb);
  // fused QKV projection
  gemm_bt<16><<<dim3(32,24), 256, 0, stream>>>(xnb, wqkv, 3072, 1024, nullptr, nullptr, nullptr, nullptr, qkvb);
  // flash attention
  attn_k<<<dim3(SB/64, NH, NB), 256, 0, stream>>>(qkvb, ctxb);
  // out = ctx @ Wo^T + inputs  (f32 -> d_out)
  gemm_bt<4><<<dim3(32,8), 256, 0, stream>>>(ctxb, wo, 1024, 1024, nullptr, inputs, nullptr, out, nullptr);
  // lnF -> bf16
  ln_k<2><<<NTOK, 256, 0, stream>>>(out, nullptr, lnF_g, lnF_b, nullptr, nullptr, lnfb);
  // inter = relu(lnF @ W1^T + b1) (bf16)
  gemm_bt<19><<<dim3(32,32), 256, 0, stream>>>(lnfb, w1p, 4096, 1024, b1, nullptr, nullptr, nullptr, interb);
  // final = (inter @ W2^T + b2)*mask + out  -> d_out
  gemm_bt<13><<<dim3(32,8), 256, 0, stream>>>(interb, w2p, 1024, 4096, b2, out, ffnmask, out, nullptr);
}

// Round 2
// 411.629 us; speedup vs baseline: 1.3487x; 1.3487x over previous
//
#include <hip/hip_runtime.h>
#include <hip/hip_bf16.h>
#include <cstdint>
#include <cstddef>

// TransformerEncoderLayer: B=2 S=2048 D=1024 H=16 DH=64 DFF=4096, fp32 in/out.
// Round 1: attention rewrite — swapped QK^T (keys lane-local => in-register
// softmax), KVBLK=64 / QBLK=32 per wave, K via global_load_lds + XOR swizzle,
// packed+swizzled V transpose, K/V prefetch double-buffer, XCD-aware grid.

#define SB 2048
#define DD 1024
#define NB 2
#define NH 16
#define DFF_ 4096
#define NTOK (NB*SB)   // 4096
#define SP (SB+2)      // 2050 (padded rows for conv halo)

typedef unsigned short u16;
typedef unsigned int u32;
typedef float f32x4 __attribute__((ext_vector_type(4)));
typedef short s16x8 __attribute__((ext_vector_type(8)));

__device__ __forceinline__ u16 f2b(float f){
  uint32_t u = __builtin_bit_cast(uint32_t, f);
  return (u16)((u + 0x7fffu + ((u >> 16) & 1u)) >> 16);  // RNE
}

// ---------------- workspace layout (bytes) ----------------
constexpr size_t OFF_CW1   = 0;                                     // 3x1024x1024 bf16
constexpr size_t OFF_CW2   = OFF_CW1 + 3ull*1024*1024*2;
constexpr size_t OFF_WQKV  = OFF_CW2 + 3ull*1024*1024*2;            // 3072x1024 bf16 (q scaled 1/8)
constexpr size_t OFF_WO    = OFF_WQKV + 3072ull*1024*2;
constexpr size_t OFF_W1    = OFF_WO + 1024ull*1024*2;
constexpr size_t OFF_W2    = OFF_W1 + 4096ull*1024*2;
constexpr size_t OFF_PRE   = OFF_W2 + 4096ull*1024*2;               // f32 4096x1024
constexpr size_t OFF_QKVB  = OFF_PRE + (size_t)NTOK*1024*4;         // bf16 4096x3072
constexpr size_t OFF_INTER = OFF_PRE;                               // alias: bf16 4096x4096 (pre+qkvb dead)
constexpr size_t OFF_XPAD  = OFF_QKVB + (size_t)NTOK*3072*2;        // bf16 2x2050x1024
constexpr size_t OFF_LNF   = OFF_XPAD;                              // alias (xpad dead after conv1)
constexpr size_t OFF_HPAD  = OFF_XPAD + (size_t)NB*SP*1024*2;       // bf16 2x2050x1024
constexpr size_t OFF_CTX   = OFF_HPAD;                              // alias (hpad dead after conv2)
constexpr size_t OFF_INPUTS= OFF_HPAD + (size_t)NB*SP*1024*2;       // f32 4096x1024
constexpr size_t OFF_XN    = OFF_INPUTS + (size_t)NTOK*1024*4;      // bf16 4096x1024

// ---------------- pack kernels ----------------
__global__ void pack_scale_k(const float* __restrict__ in, u16* __restrict__ out, int n, float scale){
  int i = blockIdx.x*256 + threadIdx.x;
  if (i < n) out[i] = f2b(in[i]*scale);
}

// w[o][i][t] (D,D,3) -> out[t][o][i] bf16
__global__ void pack_convw_k(const float* __restrict__ w, u16* __restrict__ out){
  int i = blockIdx.x*256 + threadIdx.x;   // over 3*1024*1024
  int t = i >> 20;
  int rem = i & 1048575;
  int o = rem >> 10;
  int c = rem & 1023;
  out[i] = f2b(w[o*3072 + c*3 + t]);
}

// x f32 (B,S,D) -> xpad bf16 (B,S+2,D), zero halo rows
__global__ void pad_x_k(const float* __restrict__ x, u16* __restrict__ xp){
  int row = blockIdx.x;  // 0..NB*SP-1
  int tid = threadIdx.x;
  int b = row / SP, s = row - b*SP;
  ushort4 st;
  if (s == 0 || s == SP-1){ st.x=0; st.y=0; st.z=0; st.w=0; }
  else {
    float4 v = ((const float4*)(x + ((size_t)b*SB + s-1)*DD))[tid];
    st.x=f2b(v.x); st.y=f2b(v.y); st.z=f2b(v.z); st.w=f2b(v.w);
  }
  ((ushort4*)(xp + (size_t)row*DD))[tid] = st;
}

// ---------------- LayerNorm ----------------
// MODE 0: relu(in+cb) -> LN -> bf16 PADDED out (grid NB*SP, halo rows zeroed)
// MODE 1: relu(in+cb) -> LN -> + resid -> f32 out (grid NTOK)
// MODE 2: LN(in) -> bf16 out (grid NTOK)
template<int MODE>
__global__ __launch_bounds__(256) void ln_k(const float* __restrict__ in, const float* __restrict__ cb,
    const float* __restrict__ g, const float* __restrict__ be, const float* __restrict__ resid,
    float* __restrict__ outf, u16* __restrict__ outb)
{
  int row = blockIdx.x, tid = threadIdx.x;
  int inrow = row;
  if (MODE == 0){
    int b = row / SP, s = row - b*SP;
    if (s == 0 || s == SP-1){
      ushort4 z; z.x=0; z.y=0; z.z=0; z.w=0;
      ((ushort4*)(outb + (size_t)row*DD))[tid] = z;
      return;
    }
    inrow = b*SB + s - 1;
  }
  float4 v = ((const float4*)(in + (size_t)inrow*DD))[tid];
  if (MODE <= 1){
    float4 c = ((const float4*)cb)[tid];
    v.x = fmaxf(v.x + c.x, 0.f);
    v.y = fmaxf(v.y + c.y, 0.f);
    v.z = fmaxf(v.z + c.z, 0.f);
    v.w = fmaxf(v.w + c.w, 0.f);
  }
  float s1 = v.x+v.y+v.z+v.w;
  float s2 = v.x*v.x + v.y*v.y + v.z*v.z + v.w*v.w;
  #pragma unroll
  for (int d=32; d>=1; d>>=1){ s1 += __shfl_down(s1, d); s2 += __shfl_down(s2, d); }
  __shared__ float red[8];
  int wid = tid >> 6, lane = tid & 63;
  if (lane==0){ red[wid] = s1; red[4+wid] = s2; }
  __syncthreads();
  s1 = red[0]+red[1]+red[2]+red[3];
  s2 = red[4]+red[5]+red[6]+red[7];
  float mu = s1 * (1.f/DD);
  float var = s2 * (1.f/DD) - mu*mu;
  float rs = rsqrtf(var + 1e-6f);
  float4 gg = ((const float4*)g)[tid];
  float4 bb = ((const float4*)be)[tid];
  float o0 = (v.x-mu)*rs*gg.x + bb.x;
  float o1 = (v.y-mu)*rs*gg.y + bb.y;
  float o2 = (v.z-mu)*rs*gg.z + bb.z;
  float o3 = (v.w-mu)*rs*gg.w + bb.w;
  if (MODE == 1){
    float4 rr = ((const float4*)(resid + (size_t)inrow*DD))[tid];
    float4 o; o.x=o0+rr.x; o.y=o1+rr.y; o.z=o2+rr.z; o.w=o3+rr.w;
    ((float4*)(outf + (size_t)inrow*DD))[tid] = o;
  } else {
    ushort4 st; st.x=f2b(o0); st.y=f2b(o1); st.z=f2b(o2); st.w=f2b(o3);
    ((ushort4*)(outb + (size_t)row*DD))[tid] = st;
  }
}

// ---------------- GEMM core (C = A @ B^T), bf16 in, fp32 accum ----------------
// BM=BN=128, BK=64, 256 threads (4 waves, 2x2), mfma 16x16x32 bf16.
// LDS layout: [128 rows][64 cols] bf16 (128B rows), XOR-swizzle byte^=((row&7)<<4)
// applied by pre-swizzling the GLOBAL source address (global_load_lds writes linearly).

__device__ __forceinline__ void glds16(const u16* g, u16* l){
  __builtin_amdgcn_global_load_lds((const __attribute__((address_space(1))) void*)g,
                                   (__attribute__((address_space(3))) void*)l, 16, 0, 0);
}

__device__ __forceinline__ void stage_tile(const u16* __restrict__ src, int strideK, u16* lds, int wid, int lane){
  #pragma unroll
  for (int i=0;i<4;i++){
    int chunk = (wid<<2) + i;            // 16 chunks x 1KB cover 128x64 bf16
    int p = (chunk<<10) + (lane<<4);     // linear LDS byte this lane fills
    int row = p >> 7;
    int clg = (p & 127) ^ ((row & 7) << 4);   // logical col byte stored here
    glds16(src + (size_t)row*strideK + (clg>>1), lds + (chunk<<9));
  }
}

__device__ __forceinline__ void kstep_mfma(const u16* As, const u16* Bs, int wr, int wc, int lr, int hi, f32x4 acc[4][4]){
  s16x8 af[2][4], bf[2][4];
  #pragma unroll
  for (int ks=0; ks<2; ++ks){
    #pragma unroll
    for (int m=0;m<4;m++){
      int r = (wr<<6)+(m<<4)+lr;
      int off = (r<<7) + ((((ks<<6)+(hi<<4))) ^ ((r&7)<<4));
      af[ks][m] = *(const s16x8*)((const char*)As + off);
    }
    #pragma unroll
    for (int n=0;n<4;n++){
      int r = (wc<<6)+(n<<4)+lr;
      int off = (r<<7) + ((((ks<<6)+(hi<<4))) ^ ((r&7)<<4));
      bf[ks][n] = *(const s16x8*)((const char*)Bs + off);
    }
  }
  #pragma unroll
  for (int ks=0;ks<2;++ks)
    #pragma unroll
    for (int m=0;m<4;m++)
      #pragma unroll
      for (int n=0;n<4;n++)
        acc[m][n] = __builtin_amdgcn_mfma_f32_16x16x32_bf16(af[ks][m], bf[ks][n], acc[m][n], 0,0,0);
}

// EPI flags: 1=bias[col], 2=relu, 4=+resid f32[row*N+col], 8=*rowmask[row], 16=bf16 out (else f32)
template<int EPI>
__device__ __forceinline__ void epilogue(f32x4 acc[4][4], int m0,int n0,int N,int wr,int wc,int lr,int hi,
    const float* __restrict__ bias, const float* __restrict__ resid, const float* __restrict__ rowmask,
    float* __restrict__ Cf, u16* __restrict__ Cb)
{
  #pragma unroll
  for (int m=0;m<4;m++){
    #pragma unroll
    for (int r=0;r<4;r++){
      int row = m0 + (wr<<6) + (m<<4) + (hi<<2) + r;
      float rm = (EPI&8) ? rowmask[row] : 1.f;
      #pragma unroll
      for (int n=0;n<4;n++){
        int col = n0 + (wc<<6) + (n<<4) + lr;
        float v = acc[m][n][r];
        if (EPI&1) v += bias[col];
        if (EPI&2) v = fmaxf(v, 0.f);
        if (EPI&8) v *= rm;
        if (EPI&4) v += resid[(size_t)row*N + col];
        if (EPI&16) Cb[(size_t)row*N + col] = f2b(v);
        else        Cf[(size_t)row*N + col] = v;
      }
    }
  }
}

template<int EPI>
__global__ __launch_bounds__(256) void gemm_bt(const u16* __restrict__ A, const u16* __restrict__ Bm,
    int N, int K, const float* __restrict__ bias, const float* __restrict__ resid,
    const float* __restrict__ rowmask, float* __restrict__ Cf, u16* __restrict__ Cb)
{
  __shared__ __attribute__((aligned(16))) u16 As[128*64];
  __shared__ __attribute__((aligned(16))) u16 Bs[128*64];
  int tid=threadIdx.x, wid=tid>>6, lane=tid&63, lr=lane&15, hi=lane>>4;
  int wr=wid>>1, wc=wid&1;
  int m0=blockIdx.x<<7, n0=blockIdx.y<<7;
  f32x4 acc[4][4] = {};
  const u16* Ab = A + (size_t)m0*K;
  const u16* Bb = Bm + (size_t)n0*K;
  int nk = K >> 6;
  for (int kt=0; kt<nk; ++kt){
    stage_tile(Ab + (kt<<6), K, As, wid, lane);
    stage_tile(Bb + (kt<<6), K, Bs, wid, lane);
    __syncthreads();
    kstep_mfma(As, Bs, wr, wc, lr, hi, acc);
    __syncthreads();
  }
  epilogue<EPI>(acc, m0, n0, N, wr, wc, lr, hi, bias, resid, rowmask, Cf, Cb);
}

// conv as GEMM over padded activations: out[s][o] = sum_t sum_i xp[b][s+t][i]*W3[t][o][i]
__global__ __launch_bounds__(256) void conv_gemm(const u16* __restrict__ xp, const u16* __restrict__ W3,
    float* __restrict__ Cf)
{
  __shared__ __attribute__((aligned(16))) u16 As[128*64];
  __shared__ __attribute__((aligned(16))) u16 Bs[128*64];
  int tid=threadIdx.x, wid=tid>>6, lane=tid&63, lr=lane&15, hi=lane>>4;
  int wr=wid>>1, wc=wid&1;
  int m0=blockIdx.x<<7, n0=blockIdx.y<<7;
  int bb = m0 >> 11, ss = m0 & 2047;   // 2048 rows per batch; tiles never cross batches
  f32x4 acc[4][4] = {};
  for (int tap=0; tap<3; ++tap){
    const u16* Ab = xp + ((size_t)bb*SP + ss + tap)*DD;
    const u16* Bb = W3 + ((size_t)tap<<20) + ((size_t)n0<<10);
    for (int kt=0; kt<16; ++kt){
      stage_tile(Ab + (kt<<6), DD, As, wid, lane);
      stage_tile(Bb + (kt<<6), DD, Bs, wid, lane);
      __syncthreads();
      kstep_mfma(As, Bs, wr, wc, lr, hi, acc);
      __syncthreads();
    }
  }
  epilogue<0>(acc, m0, n0, DD, wr, wc, lr, hi, nullptr, nullptr, nullptr, Cf, nullptr);
}

// ---------------- flash attention (round 1 rewrite) ----------------
// qkv: [NTOK][3072] bf16 rows = [q(1024) k(1024) v(1024)], q pre-scaled 1/8.
// Grid: 512 blocks 1D; hb=bid&31 (h,b), qt=bid>>5 -> all q-tiles of one (b,h)
// share an XCD (bid%8 const). 256 threads = 4 waves; wave owns 32 q-rows
// (2 sub-tiles u of 16). KV tile = 64 keys, 32 iterations.
// Swapped QK^T: S^T = mfma(K, Q) -> lane holds 16 scores for q=lane&15,
// keys kg*16+4*hi+r (lane-local reduction + 2 shfl_xor).
// K: double-buffered LDS [64][128B] XOR-swizzled, staged via global_load_lds
//    with pre-swizzled global source (prefetched one tile ahead).
// V: register-prefetched, transposed into Vt[d][key] (stride 72 u16) with
//    packed b32 writes, key-col XOR-swizzled by (d>>3)&7 -> ~2-way banks.
// P: per-wave LDS [16][72], packed ushort4 writes (4 consecutive keys/lane).
__global__ __launch_bounds__(256,2) void attn_k(const u16* __restrict__ qkv, u16* __restrict__ ctx)
{
  __shared__ __attribute__((aligned(16))) u16 Ks[2][64*64];
  __shared__ __attribute__((aligned(16))) u16 Vt[64*72];
  __shared__ __attribute__((aligned(16))) u16 Ps[8][16*72];
  int tid=threadIdx.x, wid=tid>>6, lane=tid&63, lr=lane&15, hi=lane>>4;
  int bid = blockIdx.x;
  int hb = bid & 31, qt = bid >> 5;
  int h = hb & 15, b = hb >> 4;
  int q0 = (qt<<7) + (wid<<5);
  size_t kbase = ((size_t)b*SB)*3072 + 1024 + (h<<6);
  size_t vbase = kbase + 1024;

  // Q fragments: aq[u] holds Q[q0+u*16+lr][hi*8..+7 (+32)]
  s16x8 aq[2][2];
  #pragma unroll
  for (int u=0;u<2;u++){
    size_t qrow = ((size_t)b*SB + q0 + (u<<4) + lr)*3072 + (h<<6);
    aq[u][0] = *(const s16x8*)(qkv + qrow + (hi<<3));
    aq[u][1] = *(const s16x8*)(qkv + qrow + 32 + (hi<<3));
  }

  int k2v = tid>>3;            // key pair 2*k2v, 2*k2v+1
  int d0v = (tid&7)<<3;        // d block of 8
  int gsw = tid&7;             // = (d>>3)&7 for all d this thread writes

  // prologue: stage K tile 0 into Ks[0], load V tile 0 into regs
  #pragma unroll
  for (int i=0;i<2;i++){
    int cb = (i<<12) + (wid<<10);
    int p = cb + (lane<<4);
    int row = p>>7;
    int colb = (p&127) ^ ((row&7)<<4);
    glds16(qkv + kbase + (size_t)row*3072 + (colb>>1), (u16*)((char*)Ks[0] + cb));
  }
  s16x8 v0 = *(const s16x8*)(qkv + vbase + (size_t)(2*k2v)*3072 + d0v);
  s16x8 v1 = *(const s16x8*)(qkv + vbase + (size_t)(2*k2v+1)*3072 + d0v);

  float m_q[2] = {-1e30f,-1e30f}, l_q[2] = {0.f,0.f};
  f32x4 acc[2][4] = {};
  int cur = 0;
  for (int kt=0; kt<32; ++kt){
    __syncthreads();           // Ks[cur] staged (vmcnt drained); prev Vt reads done
    // transpose V tile into Vt (packed pairs, swizzled key column)
    #pragma unroll
    for (int i=0;i<8;i++){
      int d = d0v + i;
      u32 val = ((u32)(u16)v0[i]) | (((u32)(u16)v1[i])<<16);
      *(u32*)((char*)Vt + d*144 + ((k2v<<2) ^ (gsw<<4))) = val;
    }
    __syncthreads();           // Vt ready
    // prefetch next tile (K -> other LDS buffer, V -> regs); drains at next top barrier
    int k0n = ((kt+1 < 32) ? kt+1 : kt) << 6;
    #pragma unroll
    for (int i=0;i<2;i++){
      int cb = (i<<12) + (wid<<10);
      int p = cb + (lane<<4);
      int row = p>>7;
      int colb = (p&127) ^ ((row&7)<<4);
      glds16(qkv + kbase + (size_t)(k0n+row)*3072 + (colb>>1), (u16*)((char*)Ks[cur^1] + cb));
    }
    v0 = *(const s16x8*)(qkv + vbase + (size_t)(k0n + 2*k2v)*3072 + d0v);
    v1 = *(const s16x8*)(qkv + vbase + (size_t)(k0n + 2*k2v+1)*3072 + d0v);

    // QK^T (swapped): s[u][kg] = S^T tile, score(key=kg*16+4hi+r, q=lr)
    const char* Kb = (const char*)Ks[cur];
    f32x4 s[2][4];
    #pragma unroll
    for (int kg=0; kg<4; kg++){
      int row = (kg<<4) + lr;
      int sw = (row&7)<<4;
      s16x8 ka0 = *(const s16x8*)(Kb + (row<<7) + ((hi<<4) ^ sw));
      s16x8 ka1 = *(const s16x8*)(Kb + (row<<7) + ((64+(hi<<4)) ^ sw));
      #pragma unroll
      for (int u=0;u<2;u++){
        f32x4 z = {0.f,0.f,0.f,0.f};
        z = __builtin_amdgcn_mfma_f32_16x16x32_bf16(ka0, aq[u][0], z, 0,0,0);
        z = __builtin_amdgcn_mfma_f32_16x16x32_bf16(ka1, aq[u][1], z, 0,0,0);
        s[u][kg] = z;
      }
    }
    // online softmax per q-subtile (keys lane-local: 16 in-reg + 2 shuffles)
    #pragma unroll
    for (int u=0;u<2;u++){
      float mt = s[u][0][0];
      #pragma unroll
      for (int kg=0;kg<4;kg++)
        #pragma unroll
        for (int r=0;r<4;r++) mt = fmaxf(mt, s[u][kg][r]);
      mt = fmaxf(mt, __shfl_xor(mt,16));
      mt = fmaxf(mt, __shfl_xor(mt,32));
      float mn = fmaxf(m_q[u], mt);
      float al = __expf(m_q[u]-mn);
      m_q[u] = mn;
      float sm = 0.f;
      #pragma unroll
      for (int kg=0;kg<4;kg++){
        float p0=__expf(s[u][kg][0]-mn), p1=__expf(s[u][kg][1]-mn);
        float p2=__expf(s[u][kg][2]-mn), p3=__expf(s[u][kg][3]-mn);
        sm += (p0+p1)+(p2+p3);
        ushort4 pk; pk.x=f2b(p0); pk.y=f2b(p1); pk.z=f2b(p2); pk.w=f2b(p3);
        *(ushort4*)((char*)Ps[(wid<<1)+u] + lr*144 + (kg<<5) + (hi<<3)) = pk;
      }
      sm += __shfl_xor(sm,16); sm += __shfl_xor(sm,32);
      l_q[u] = l_q[u]*al + sm;
      // broadcast al into PV domain (acc row q = 4*hi+r) and rescale
      int ali = __builtin_bit_cast(int, al);
      #pragma unroll
      for (int r=0;r<4;r++){
        float alr = __builtin_bit_cast(float, __builtin_amdgcn_ds_bpermute((((hi<<2)+r)<<2), ali));
        #pragma unroll
        for (int cg=0;cg<4;cg++) acc[u][cg][r] *= alr;
      }
    }
    // PV: A = P[q][key] (per-wave LDS), B = V[key][d] (Vt), shared vb across u
    #pragma unroll
    for (int t=0;t<2;t++){
      s16x8 pa[2];
      #pragma unroll
      for (int u=0;u<2;u++)
        pa[u] = *(const s16x8*)((char*)Ps[(wid<<1)+u] + lr*144 + (t<<6) + (hi<<4));
      #pragma unroll
      for (int cg=0;cg<4;cg++){
        int d = (cg<<4)+lr;
        s16x8 vb = *(const s16x8*)((char*)Vt + d*144 + (((t<<6)+(hi<<4)) ^ (((d>>3)&7)<<4)));
        #pragma unroll
        for (int u=0;u<2;u++)
          acc[u][cg] = __builtin_amdgcn_mfma_f32_16x16x32_bf16(pa[u], vb, acc[u][cg], 0,0,0);
      }
    }
    cur ^= 1;
  }
  // epilogue: normalize (1/l broadcast to PV domain) and store ctx bf16
  #pragma unroll
  for (int u=0;u<2;u++){
    float inv = 1.f/l_q[u];
    int ii = __builtin_bit_cast(int, inv);
    size_t obase = ((size_t)b*SB + q0 + (u<<4))*DD + (h<<6);
    #pragma unroll
    for (int r=0;r<4;r++){
      float ir = __builtin_bit_cast(float, __builtin_amdgcn_ds_bpermute((((hi<<2)+r)<<2), ii));
      #pragma unroll
      for (int cg=0;cg<4;cg++)
        ctx[obase + (size_t)((hi<<2)+r)*DD + (cg<<4) + lr] = f2b(acc[u][cg][r]*ir);
    }
  }
}

// ---------------- launch ----------------
extern "C" void kernel_launch(void* const* d_in, const int* in_sizes, int n_in,
                              void* d_out, int out_size, void* d_ws, size_t ws_size,
                              hipStream_t stream)
{
  (void)in_sizes; (void)n_in; (void)out_size; (void)ws_size;
  const float* x       = (const float*)d_in[0];
  const float* ffnmask = (const float*)d_in[2];
  const float* conv1_w = (const float*)d_in[3];
  const float* conv1_b = (const float*)d_in[4];
  const float* ln1_g   = (const float*)d_in[5];
  const float* ln1_b   = (const float*)d_in[6];
  const float* conv2_w = (const float*)d_in[7];
  const float* conv2_b = (const float*)d_in[8];
  const float* ln2_g   = (const float*)d_in[9];
  const float* ln2_b   = (const float*)d_in[10];
  const float* lnA_g   = (const float*)d_in[11];
  const float* lnA_b   = (const float*)d_in[12];
  const float* Wq      = (const float*)d_in[13];
  const float* Wk      = (const float*)d_in[14];
  const float* Wv      = (const float*)d_in[15];
  const float* Wo      = (const float*)d_in[16];
  const float* lnF_g   = (const float*)d_in[17];
  const float* lnF_b   = (const float*)d_in[18];
  const float* W1      = (const float*)d_in[19];
  const float* b1      = (const float*)d_in[20];
  const float* W2      = (const float*)d_in[21];
  const float* b2      = (const float*)d_in[22];
  float* out = (float*)d_out;
  char* ws = (char*)d_ws;
  u16*  cw1    = (u16*)(ws + OFF_CW1);
  u16*  cw2    = (u16*)(ws + OFF_CW2);
  u16*  wqkv   = (u16*)(ws + OFF_WQKV);
  u16*  wo     = (u16*)(ws + OFF_WO);
  u16*  w1p    = (u16*)(ws + OFF_W1);
  u16*  w2p    = (u16*)(ws + OFF_W2);
  float* pre   = (float*)(ws + OFF_PRE);
  u16*  qkvb   = (u16*)(ws + OFF_QKVB);
  u16*  interb = (u16*)(ws + OFF_INTER);
  u16*  xpad   = (u16*)(ws + OFF_XPAD);
  u16*  lnfb   = (u16*)(ws + OFF_LNF);
  u16*  hpad   = (u16*)(ws + OFF_HPAD);
  u16*  ctxb   = (u16*)(ws + OFF_CTX);
  float* inputs= (float*)(ws + OFF_INPUTS);
  u16*  xnb    = (u16*)(ws + OFF_XN);

  // weight packs (bf16); q-scale 1/sqrt(64) folded into Wq
  pack_convw_k<<<12288, 256, 0, stream>>>(conv1_w, cw1);
  pack_convw_k<<<12288, 256, 0, stream>>>(conv2_w, cw2);
  pack_scale_k<<<4096, 256, 0, stream>>>(Wq, wqkv,             1024*1024, 0.125f);
  pack_scale_k<<<4096, 256, 0, stream>>>(Wk, wqkv + (1u<<20),  1024*1024, 1.f);
  pack_scale_k<<<4096, 256, 0, stream>>>(Wv, wqkv + (2u<<20),  1024*1024, 1.f);
  pack_scale_k<<<4096, 256, 0, stream>>>(Wo, wo,               1024*1024, 1.f);
  pack_scale_k<<<16384, 256, 0, stream>>>(W1, w1p, 4096*1024, 1.f);
  pack_scale_k<<<16384, 256, 0, stream>>>(W2, w2p, 4096*1024, 1.f);
  pad_x_k<<<NB*SP, 256, 0, stream>>>(x, xpad);

  // conv1 -> relu -> LN1 (padded bf16 for conv2)
  conv_gemm<<<dim3(32,8), 256, 0, stream>>>(xpad, cw1, pre);
  ln_k<0><<<NB*SP, 256, 0, stream>>>(pre, conv1_b, ln1_g, ln1_b, nullptr, nullptr, hpad);
  // conv2 -> relu -> LN2 -> +x  => inputs (f32)
  conv_gemm<<<dim3(32,8), 256, 0, stream>>>(hpad, cw2, pre);
  ln_k<1><<<NTOK, 256, 0, stream>>>(pre, conv2_b, ln2_g, ln2_b, x, inputs, nullptr);
  // lnA -> xn (bf16)
  ln_k<2><<<NTOK, 256, 0, stream>>>(inputs, nullptr, lnA_g, lnA_b, nullptr, nullptr, xnb);
  // fused QKV projection
  gemm_bt<16><<<dim3(32,24), 256, 0, stream>>>(xnb, wqkv, 3072, 1024, nullptr, nullptr, nullptr, nullptr, qkvb);
  // flash attention
  attn_k<<<512, 256, 0, stream>>>(qkvb, ctxb);
  // out = ctx @ Wo^T + inputs  (f32 -> d_out)
  gemm_bt<4><<<dim3(32,8), 256, 0, stream>>>(ctxb, wo, 1024, 1024, nullptr, inputs, nullptr, out, nullptr);
  // lnF -> bf16
  ln_k<2><<<NTOK, 256, 0, stream>>>(out, nullptr, lnF_g, lnF_b, nullptr, nullptr, lnfb);
  // inter = relu(lnF @ W1^T + b1) (bf16)
  gemm_bt<19><<<dim3(32,32), 256, 0, stream>>>(lnfb, w1p, 4096, 1024, b1, nullptr, nullptr, nullptr, interb);
  // final = (inter @ W2^T + b2)*mask + out  -> d_out
  gemm_bt<13><<<dim3(32,8), 256, 0, stream>>>(interb, w2p, 1024, 4096, b2, out, ffnmask, out, nullptr);
}